// Round 10
// baseline (294.645 us; speedup 1.0000x reference)
//
#include <hip/hip_runtime.h>
#include <math.h>

#define HID 128
#define TPB 512   // 8 waves/block; 2 blocks/CU (77KB LDS) -> 4 waves/SIMD
#define GRIDB 512 // persistent; 128 samples per block-chunk; nchunk = 2

typedef __bf16 bf16;
typedef bf16 bf16x8 __attribute__((ext_vector_type(8)));
typedef bf16 bf16x2 __attribute__((ext_vector_type(2)));
typedef float floatx4 __attribute__((ext_vector_type(4)));
typedef unsigned int u32;

__device__ __forceinline__ float fast_tanh(float x) {
    float e = __builtin_amdgcn_exp2f(x * 2.885390081777927f); // exp(2x)
    return 1.0f - 2.0f / (e + 1.0f);
}
__device__ __forceinline__ u32 pkbf(float lo, float hi) {
    bf16x2 t = {(bf16)lo, (bf16)hi};
    return __builtin_bit_cast(u32, t);
}
__device__ __forceinline__ float unplo(u32 p) {
    return __builtin_bit_cast(float, p << 16);
}
__device__ __forceinline__ float unphi(u32 p) {
    return __builtin_bit_cast(float, p & 0xffff0000u);
}
union FragU { bf16x8 v; u32 u[4]; };

// T1: C/D-layout -> B-frag layout, fully intra-wave.
//   D tile t: lane(q,c) reg r holds M[row=16t+4q+r][col=c]   (rows = next-GEMM k)
//   frag tile T: lane(q,c) idx holds M[k=32T+8q+idx][n=c]
//   k=32T+8q+idx => src tile 2T+(q>>1), src lane (2(q&1)+(idx>>2))*16+c, reg idx&3
// __shfl evaluates its operand in the SOURCE lane, so the dest-dependent tile
// select (q>>1) happens AFTER the shuffle via cndmask.
__device__ __forceinline__ bf16x8 t1frag(u32 pA0, u32 pA1, u32 pB0, u32 pB1,
                                         bool hi, int a1, int a2) {
    u32 A0a = (u32)__shfl((int)pA0, a1);
    u32 A1a = (u32)__shfl((int)pA1, a1);
    u32 B0a = (u32)__shfl((int)pB0, a1);
    u32 B1a = (u32)__shfl((int)pB1, a1);
    u32 A0b = (u32)__shfl((int)pA0, a2);
    u32 A1b = (u32)__shfl((int)pA1, a2);
    u32 B0b = (u32)__shfl((int)pB0, a2);
    u32 B1b = (u32)__shfl((int)pB1, a2);
    FragU f;
    f.u[0] = hi ? B0a : A0a;  // idx 0,1  (regs 0,1 of src tile)
    f.u[1] = hi ? B1a : A1a;  // idx 2,3  (regs 2,3)
    f.u[2] = hi ? B0b : A0b;  // idx 4,5
    f.u[3] = hi ? B1b : A1b;  // idx 6,7
    return f.v;
}
__device__ __forceinline__ bf16x8 ldfrag(const bf16* base, int tile, int lane) {
    return *reinterpret_cast<const bf16x8*>(&base[(tile * 64 + lane) * 8]);
}

// Wave w owns sample stripe st=w (16 samples) end-to-end. Zero barriers in loop.
// GEMM1t: Z1^T = W1e^T @ feat^T (K=32, bias as 5th feat row) -> 8 MFMA
// GEMM2t: Z2^T = W2^T @ H1^T  (A: sW2A, B: H1 frags in regs)  -> 32 MFMA
// GEMM3t: S^T  = W2  @ G2^T   (A: sW2R, B: G2 frags in regs)  -> 32 MFMA
// GEMM4t: dV^T = W1  @ G1^T   (A: sW1f, B: G1 frags in regs)  -> 4 MFMA

__global__ __launch_bounds__(TPB, 4)
void lnn_kernel(const float* __restrict__ X,
                const float* __restrict__ W1,
                const float* __restrict__ b1,
                const float* __restrict__ b2,
                const float* __restrict__ W3,
                const float* __restrict__ W2,
                float* __restrict__ out,
                int B, int nchunk)
{
    __shared__ __align__(16) bf16 sW2A[2048 * 8]; // 32KB W2^T A-frags [(jt*4+kt)]
    __shared__ __align__(16) bf16 sW2R[2048 * 8]; // 32KB W2 row A-frags [(it*4+jt2)]
    __shared__ __align__(16) bf16 sW1e[512 * 8];  // 8KB  W1ext^T A-frags [jt], K=32(5 used)
    __shared__ __align__(16) bf16 sW1f[256 * 8];  // 4KB  W1 A-frags [it3], m=c<4
    __shared__ __align__(16) float sB2[HID];
    __shared__ __align__(16) float sW3[HID];

    const int tid = threadIdx.x;
    const int w   = tid >> 6;
    const int lane = tid & 63;
    const int c   = lane & 15;  // column: sample-in-stripe / m-row
    const int q   = lane >> 4;  // quad
    const int a1  = 32 * (q & 1) + c;  // T1 source lanes
    const int a2  = a1 + 16;
    const bool thi = (q >> 1) != 0;    // T1 dest-side tile select

    // ------ one-time staging; ALL arrays covered by 512 threads (R9 bugfix) ------
    #pragma unroll
    for (int tt = 0; tt < 4; ++tt) {
        int e = tid + tt * TPB;           // 0..2047
        int t = e >> 6, l = e & 63;
        int lr = l & 15, qq = l >> 4;
        {   // sW2A tile (jt=t>>2, kt=t&3): A[m=16jt+lr][k=32kt+8qq+idx]=W2[k][m]
            int jt = t >> 2, kt = t & 3;
            bf16x8 f;
            #pragma unroll
            for (int idx = 0; idx < 8; ++idx)
                f[idx] = (bf16)W2[(32 * kt + 8 * qq + idx) * HID + 16 * jt + lr];
            *reinterpret_cast<bf16x8*>(&sW2A[e * 8]) = f;
        }
        {   // sW2R tile (it=t>>2, jt2=t&3): A[m=16it+lr][k=32jt2+8qq+idx]=W2[m][k]
            int it = t >> 2, jt2 = t & 3;
            const float4* rp = reinterpret_cast<const float4*>(
                &W2[(16 * it + lr) * HID + 32 * jt2 + 8 * qq]);
            float4 r0 = rp[0], r1 = rp[1];
            bf16x8 g;
            g[0]=(bf16)r0.x; g[1]=(bf16)r0.y; g[2]=(bf16)r0.z; g[3]=(bf16)r0.w;
            g[4]=(bf16)r1.x; g[5]=(bf16)r1.y; g[6]=(bf16)r1.z; g[7]=(bf16)r1.w;
            *reinterpret_cast<bf16x8*>(&sW2R[e * 8]) = g;
        }
    }
    {   // sW1e (512 lines): tile jt=tid>>6: A[m=16jt+lr][k=8qq+idx]=W1e[k][m]
        int t = tid >> 6, l = tid & 63;
        int lr = l & 15, qq = l >> 4;
        bf16x8 f = {};
        if (qq == 0) {
            #pragma unroll
            for (int idx = 0; idx < 4; ++idx)
                f[idx] = (bf16)W1[idx * HID + 16 * t + lr];
            f[4] = (bf16)b1[16 * t + lr];
        }
        *reinterpret_cast<bf16x8*>(&sW1e[tid * 8]) = f;
    }
    if (tid < 256) { // sW1f (256 lines): tile it3: A[m=lr(<4)][k=32it3+8qq+idx]=W1[m][k]
        int t = tid >> 6, l = tid & 63;
        int lr = l & 15, qq = l >> 4;
        bf16x8 f = {};
        if (lr < 4) {
            const float4* wp = reinterpret_cast<const float4*>(
                &W1[lr * HID + 32 * t + 8 * qq]);
            float4 a = wp[0], b = wp[1];
            f[0]=(bf16)a.x; f[1]=(bf16)a.y; f[2]=(bf16)a.z; f[3]=(bf16)a.w;
            f[4]=(bf16)b.x; f[5]=(bf16)b.y; f[6]=(bf16)b.z; f[7]=(bf16)b.w;
        }
        *reinterpret_cast<bf16x8*>(&sW1f[tid * 8]) = f;
    } else if (tid < 384) {
        sB2[tid - 256] = b2[tid - 256];
    } else {
        sW3[tid - 384] = W3[tid - 384];
    }
    __syncthreads(); // the ONLY barrier

    #pragma unroll 1
    for (int ch = 0; ch < nchunk; ++ch) {
        const int s0 = (ch * GRIDB + (int)blockIdx.x) * (TPB / 4); // 128/blk
        const int g  = s0 + 16 * w + c;    // this lane's sample
        const int gc = g < B ? g : (B - 1);

        float4 x = reinterpret_cast<const float4*>(X)[gc];
        float s1v, c1v, s2v, c2v;
        __sincosf(x.x, &s1v, &c1v);
        __sincosf(x.y, &s2v, &c2v);

        // feat^T B-frag: lane(q,c) holds feat[k=8q+idx][s]; k<5 => q==0 only
        FragU fb; fb.u[0] = fb.u[1] = fb.u[2] = fb.u[3] = 0;
        if (q == 0) {
            fb.u[0] = pkbf(s1v, c1v);
            fb.u[1] = pkbf(s2v, c2v);
            fb.u[2] = pkbf(1.0f, 0.0f);
        }

        // ---- GEMM1t: Z1^T (D-layout, 8 tiles over j) ----
        floatx4 z[8];
        #pragma unroll
        for (int jt = 0; jt < 8; ++jt)
            z[jt] = __builtin_amdgcn_mfma_f32_16x16x32_bf16(
                ldfrag(sW1e, jt, lane), fb.v, floatx4{0.f,0.f,0.f,0.f}, 0, 0, 0);

        // tanh + derivative, packed pairs (D-layout)
        u32 hp[8][2], dp[8][2];
        #pragma unroll
        for (int t = 0; t < 8; ++t) {
            float h0 = fast_tanh(z[t][0]), h1 = fast_tanh(z[t][1]);
            float h2 = fast_tanh(z[t][2]), h3 = fast_tanh(z[t][3]);
            hp[t][0] = pkbf(h0, h1);            hp[t][1] = pkbf(h2, h3);
            dp[t][0] = pkbf(1.f-h0*h0, 1.f-h1*h1); dp[t][1] = pkbf(1.f-h2*h2, 1.f-h3*h3);
        }
        // T1 -> H1 B-frags (4 k-tiles)
        bf16x8 hf[4];
        #pragma unroll
        for (int T = 0; T < 4; ++T)
            hf[T] = t1frag(hp[2*T][0], hp[2*T][1], hp[2*T+1][0], hp[2*T+1][1], thi, a1, a2);

        // ---- GEMM2t: Z2^T = W2^T @ H1^T ----
        floatx4 acc[8];
        #pragma unroll
        for (int jt = 0; jt < 8; ++jt) acc[jt] = floatx4{0.f,0.f,0.f,0.f};
        #pragma unroll
        for (int kt = 0; kt < 4; ++kt)
            #pragma unroll
            for (int jt = 0; jt < 8; ++jt)
                acc[jt] = __builtin_amdgcn_mfma_f32_16x16x32_bf16(
                    ldfrag(sW2A, jt * 4 + kt, lane), hf[kt], acc[jt], 0, 0, 0);

        // ---- layer-2 activation: G2 = (1-tanh^2(Z2+b2))*W3 (D-layout) ----
        u32 gp[8][2];
        #pragma unroll
        for (int t = 0; t < 8; ++t) {
            float4 b2v = *reinterpret_cast<const float4*>(&sB2[16 * t + 4 * q]);
            float4 w3v = *reinterpret_cast<const float4*>(&sW3[16 * t + 4 * q]);
            float h0 = fast_tanh(acc[t][0] + b2v.x), h1 = fast_tanh(acc[t][1] + b2v.y);
            float h2 = fast_tanh(acc[t][2] + b2v.z), h3 = fast_tanh(acc[t][3] + b2v.w);
            gp[t][0] = pkbf((1.f-h0*h0)*w3v.x, (1.f-h1*h1)*w3v.y);
            gp[t][1] = pkbf((1.f-h2*h2)*w3v.z, (1.f-h3*h3)*w3v.w);
        }
        bf16x8 gf[4];
        #pragma unroll
        for (int T = 0; T < 4; ++T)
            gf[T] = t1frag(gp[2*T][0], gp[2*T][1], gp[2*T+1][0], gp[2*T+1][1], thi, a1, a2);

        // ---- GEMM3t: S^T = W2 @ G2^T ----
        floatx4 sa[8];
        #pragma unroll
        for (int it = 0; it < 8; ++it) sa[it] = floatx4{0.f,0.f,0.f,0.f};
        #pragma unroll
        for (int jt2 = 0; jt2 < 4; ++jt2)
            #pragma unroll
            for (int it = 0; it < 8; ++it)
                sa[it] = __builtin_amdgcn_mfma_f32_16x16x32_bf16(
                    ldfrag(sW2R, it * 4 + jt2, lane), gf[jt2], sa[it], 0, 0, 0);

        // ---- G1 = d1 * S (elementwise in D-layout), pack, T1 -> frags ----
        u32 g1p[8][2];
        #pragma unroll
        for (int t = 0; t < 8; ++t) {
            g1p[t][0] = pkbf(unplo(dp[t][0]) * sa[t][0], unphi(dp[t][0]) * sa[t][1]);
            g1p[t][1] = pkbf(unplo(dp[t][1]) * sa[t][2], unphi(dp[t][1]) * sa[t][3]);
        }
        bf16x8 g1f[4];
        #pragma unroll
        for (int T = 0; T < 4; ++T)
            g1f[T] = t1frag(g1p[2*T][0], g1p[2*T][1], g1p[2*T+1][0], g1p[2*T+1][1], thi, a1, a2);

        // ---- GEMM4t: dV^T = W1 @ G1^T (rows 0..3 = feat grads, quad 0) ----
        floatx4 dv = floatx4{0.f,0.f,0.f,0.f};
        #pragma unroll
        for (int it3 = 0; it3 < 4; ++it3)
            dv = __builtin_amdgcn_mfma_f32_16x16x32_bf16(
                ldfrag(sW1f, it3, lane), g1f[it3], dv, 0, 0, 0);

        // ---- epilogue: analytic dynamics + 2x2 solve (quad-0 lanes) ----
        if (q == 0 && g < B) {
            float w1 = x.z, w2 = x.w;
            float cosD = c1v * c2v + s1v * s2v;
            float sinD = s1v * c2v - c1v * s2v;
            float dVt1 = dv[0] * c1v - dv[1] * s1v;  // dV/dt1
            float dVt2 = dv[2] * c2v - dv[3] * s2v;  // dV/dt2
            float sT = w1 * w2 * sinD;               // dT/dt1=-sT, dT/dt2=+sT
            float cw = sinD * (w2 - w1);
            float rhs1 = (-sT - dVt1) - w2 * cw;
            float rhs2 = ( sT - dVt2) - w1 * cw;
            float det = 2.0f - cosD * cosD;          // det(M) in [1,2]
            float inv = 1.0f / det;
            float qdd1 = (rhs1 - cosD * rhs2) * inv;
            float qdd2 = (2.0f * rhs2 - cosD * rhs1) * inv;
            *reinterpret_cast<float4*>(&out[4 * g]) = make_float4(w1, w2, qdd1, qdd2);
        }
    }
}

extern "C" void kernel_launch(void* const* d_in, const int* in_sizes, int n_in,
                              void* d_out, int out_size, void* d_ws, size_t ws_size,
                              hipStream_t stream) {
    const float* X  = (const float*)d_in[0];
    const float* W1 = (const float*)d_in[1];
    const float* b1 = (const float*)d_in[2];
    const float* W2 = (const float*)d_in[3];
    const float* b2 = (const float*)d_in[4];
    const float* W3 = (const float*)d_in[5];
    // d_in[6] = b3: constant offset on V, vanishes in all gradients
    float* out = (float*)d_out;
    int B = in_sizes[0] / 4;
    int spg = GRIDB * (TPB / 4); // samples per grid-chunk
    int nchunk = (B + spg - 1) / spg;
    lnn_kernel<<<GRIDB, TPB, 0, stream>>>(X, W1, b1, b2, W3, W2, out, B, nchunk);
}

// Round 11
// 274.860 us; speedup vs baseline: 1.0720x; 1.0720x over previous
//
#include <hip/hip_runtime.h>
#include <math.h>

#define HID 128
#define TPB 512   // 8 waves/block; 2 blocks/CU (77KB LDS) -> 4 waves/SIMD
#define GRIDB 512 // persistent; 128 samples per block-chunk; nchunk = 2

typedef __bf16 bf16;
typedef bf16 bf16x8 __attribute__((ext_vector_type(8)));
typedef bf16 bf16x2 __attribute__((ext_vector_type(2)));
typedef float floatx4 __attribute__((ext_vector_type(4)));
typedef unsigned int u32;

__device__ __forceinline__ float fast_tanh(float x) {
    float e = __builtin_amdgcn_exp2f(x * 2.885390081777927f); // exp(2x)
    return 1.0f - 2.0f / (e + 1.0f);
}
__device__ __forceinline__ u32 pkbf(float lo, float hi) {
    bf16x2 t = {(bf16)lo, (bf16)hi};
    return __builtin_bit_cast(u32, t);
}
__device__ __forceinline__ float unplo(u32 p) {
    return __builtin_bit_cast(float, p << 16);
}
__device__ __forceinline__ float unphi(u32 p) {
    return __builtin_bit_cast(float, p & 0xffff0000u);
}
union FragU { bf16x8 v; u32 u[4]; };

// T1: C/D-layout -> B-frag layout, fully intra-wave (verified R10).
//   D tile t: lane(q,c) reg r holds M[row=16t+4q+r][col=c]
//   frag tile T: lane(q,c) idx holds M[k=32T+8q+idx][n=c]
//   src tile 2T+(q>>1), src lane (2(q&1)+(idx>>2))*16+c, reg idx&3.
//   Dest-side tile select AFTER the shuffle (cndmask on dest q>>1).
__device__ __forceinline__ bf16x8 t1frag(u32 pA0, u32 pA1, u32 pB0, u32 pB1,
                                         bool hi, int a1, int a2) {
    u32 A0a = (u32)__shfl((int)pA0, a1);
    u32 A1a = (u32)__shfl((int)pA1, a1);
    u32 B0a = (u32)__shfl((int)pB0, a1);
    u32 B1a = (u32)__shfl((int)pB1, a1);
    u32 A0b = (u32)__shfl((int)pA0, a2);
    u32 A1b = (u32)__shfl((int)pA1, a2);
    u32 B0b = (u32)__shfl((int)pB0, a2);
    u32 B1b = (u32)__shfl((int)pB1, a2);
    FragU f;
    f.u[0] = hi ? B0a : A0a;
    f.u[1] = hi ? B1a : A1a;
    f.u[2] = hi ? B0b : A0b;
    f.u[3] = hi ? B1b : A1b;
    return f.v;
}
__device__ __forceinline__ bf16x8 ldfrag(const bf16* base, int tile, int lane) {
    return *reinterpret_cast<const bf16x8*>(&base[(tile * 64 + lane) * 8]);
}

// Wave owns a 16-sample stripe end-to-end; zero barriers in the main loop.
// R11: tile-PAIR streaming keeps only 2 accumulator tiles live at a time,
// and the layer-1 derivative is recomputed from hp instead of stored.

__global__ __launch_bounds__(TPB, 4)
void lnn_kernel(const float* __restrict__ X,
                const float* __restrict__ W1,
                const float* __restrict__ b1,
                const float* __restrict__ b2,
                const float* __restrict__ W3,
                const float* __restrict__ W2,
                float* __restrict__ out,
                int B, int nchunk)
{
    __shared__ __align__(16) bf16 sW2A[2048 * 8]; // 32KB W2^T A-frags [(jt*4+kt)]
    __shared__ __align__(16) bf16 sW2R[2048 * 8]; // 32KB W2 row A-frags [(it*4+jt2)]
    __shared__ __align__(16) bf16 sW1e[512 * 8];  // 8KB  W1ext^T A-frags [jt]
    __shared__ __align__(16) bf16 sW1f[256 * 8];  // 4KB  W1 A-frags [it3]
    __shared__ __align__(16) float sB2[HID];
    __shared__ __align__(16) float sW3[HID];

    const int tid = threadIdx.x;
    const int w   = tid >> 6;
    const int lane = tid & 63;
    const int c   = lane & 15;
    const int q   = lane >> 4;
    const int a1  = 32 * (q & 1) + c;
    const int a2  = a1 + 16;
    const bool thi = (q >> 1) != 0;

    // ------ one-time staging (512-thread partition, verified R10) ------
    #pragma unroll
    for (int tt = 0; tt < 4; ++tt) {
        int e = tid + tt * TPB;
        int t = e >> 6, l = e & 63;
        int lr = l & 15, qq = l >> 4;
        {   // sW2A tile (jt,kt): A[m=16jt+lr][k=32kt+8qq+idx] = W2[k][m]
            int jt = t >> 2, kt = t & 3;
            bf16x8 f;
            #pragma unroll
            for (int idx = 0; idx < 8; ++idx)
                f[idx] = (bf16)W2[(32 * kt + 8 * qq + idx) * HID + 16 * jt + lr];
            *reinterpret_cast<bf16x8*>(&sW2A[e * 8]) = f;
        }
        {   // sW2R tile (it,jt2): A[m=16it+lr][k=32jt2+8qq+idx] = W2[m][k]
            int it = t >> 2, jt2 = t & 3;
            const float4* rp = reinterpret_cast<const float4*>(
                &W2[(16 * it + lr) * HID + 32 * jt2 + 8 * qq]);
            float4 r0 = rp[0], r1 = rp[1];
            bf16x8 g;
            g[0]=(bf16)r0.x; g[1]=(bf16)r0.y; g[2]=(bf16)r0.z; g[3]=(bf16)r0.w;
            g[4]=(bf16)r1.x; g[5]=(bf16)r1.y; g[6]=(bf16)r1.z; g[7]=(bf16)r1.w;
            *reinterpret_cast<bf16x8*>(&sW2R[e * 8]) = g;
        }
    }
    {   // sW1e: A[m=16jt+lr][k=8qq+idx] = W1e[k][m], bias as k=4
        int t = tid >> 6, l = tid & 63;
        int lr = l & 15, qq = l >> 4;
        bf16x8 f = {};
        if (qq == 0) {
            #pragma unroll
            for (int idx = 0; idx < 4; ++idx)
                f[idx] = (bf16)W1[idx * HID + 16 * t + lr];
            f[4] = (bf16)b1[16 * t + lr];
        }
        *reinterpret_cast<bf16x8*>(&sW1e[tid * 8]) = f;
    }
    if (tid < 256) { // sW1f: A[m=lr(<4)][k=32it3+8qq+idx] = W1[m][k]
        int t = tid >> 6, l = tid & 63;
        int lr = l & 15, qq = l >> 4;
        bf16x8 f = {};
        if (lr < 4) {
            const float4* wp = reinterpret_cast<const float4*>(
                &W1[lr * HID + 32 * t + 8 * qq]);
            float4 a = wp[0], b = wp[1];
            f[0]=(bf16)a.x; f[1]=(bf16)a.y; f[2]=(bf16)a.z; f[3]=(bf16)a.w;
            f[4]=(bf16)b.x; f[5]=(bf16)b.y; f[6]=(bf16)b.z; f[7]=(bf16)b.w;
        }
        *reinterpret_cast<bf16x8*>(&sW1f[tid * 8]) = f;
    } else if (tid < 384) {
        sB2[tid - 256] = b2[tid - 256];
    } else {
        sW3[tid - 384] = W3[tid - 384];
    }
    __syncthreads(); // the ONLY barrier

    #pragma unroll 1
    for (int ch = 0; ch < nchunk; ++ch) {
        const int s0 = (ch * GRIDB + (int)blockIdx.x) * (TPB / 4); // 128/blk
        const int g  = s0 + 16 * w + c;
        const int gc = g < B ? g : (B - 1);

        float4 x = reinterpret_cast<const float4*>(X)[gc];
        float s1v, c1v, s2v, c2v;
        __sincosf(x.x, &s1v, &c1v);
        __sincosf(x.y, &s2v, &c2v);

        // feat^T B-frag (k<5 live, quad 0 only)
        FragU fb; fb.u[0] = fb.u[1] = fb.u[2] = fb.u[3] = 0;
        if (q == 0) {
            fb.u[0] = pkbf(s1v, c1v);
            fb.u[1] = pkbf(s2v, c2v);
            fb.u[2] = pkbf(1.0f, 0.0f);
        }

        // ---- Layer 1, tile-paired: z pair -> tanh -> hp pair -> hf[T] ----
        u32 hp[8][2];     // bf16-packed h1 in D-layout (kept for dp recompute)
        bf16x8 hf[4];
        #pragma unroll
        for (int T = 0; T < 4; ++T) {
            floatx4 z0 = __builtin_amdgcn_mfma_f32_16x16x32_bf16(
                ldfrag(sW1e, 2*T,     lane), fb.v, floatx4{0.f,0.f,0.f,0.f}, 0, 0, 0);
            floatx4 z1 = __builtin_amdgcn_mfma_f32_16x16x32_bf16(
                ldfrag(sW1e, 2*T + 1, lane), fb.v, floatx4{0.f,0.f,0.f,0.f}, 0, 0, 0);
            float h00 = fast_tanh(z0[0]), h01 = fast_tanh(z0[1]);
            float h02 = fast_tanh(z0[2]), h03 = fast_tanh(z0[3]);
            float h10 = fast_tanh(z1[0]), h11 = fast_tanh(z1[1]);
            float h12 = fast_tanh(z1[2]), h13 = fast_tanh(z1[3]);
            hp[2*T][0]   = pkbf(h00, h01); hp[2*T][1]   = pkbf(h02, h03);
            hp[2*T+1][0] = pkbf(h10, h11); hp[2*T+1][1] = pkbf(h12, h13);
            hf[T] = t1frag(hp[2*T][0], hp[2*T][1], hp[2*T+1][0], hp[2*T+1][1],
                           thi, a1, a2);
        }

        // ---- GEMM2t + activation, tile-paired: only 2 acc tiles live ----
        bf16x8 gf[4];
        #pragma unroll
        for (int T = 0; T < 4; ++T) {
            floatx4 acc0 = {0.f,0.f,0.f,0.f}, acc1 = {0.f,0.f,0.f,0.f};
            #pragma unroll
            for (int kt = 0; kt < 4; ++kt) {
                acc0 = __builtin_amdgcn_mfma_f32_16x16x32_bf16(
                    ldfrag(sW2A, (2*T)*4 + kt,     lane), hf[kt], acc0, 0, 0, 0);
                acc1 = __builtin_amdgcn_mfma_f32_16x16x32_bf16(
                    ldfrag(sW2A, (2*T + 1)*4 + kt, lane), hf[kt], acc1, 0, 0, 0);
            }
            float4 b20 = *reinterpret_cast<const float4*>(&sB2[16*(2*T)   + 4*q]);
            float4 w30 = *reinterpret_cast<const float4*>(&sW3[16*(2*T)   + 4*q]);
            float4 b21 = *reinterpret_cast<const float4*>(&sB2[16*(2*T+1) + 4*q]);
            float4 w31 = *reinterpret_cast<const float4*>(&sW3[16*(2*T+1) + 4*q]);
            float h00 = fast_tanh(acc0[0] + b20.x), h01 = fast_tanh(acc0[1] + b20.y);
            float h02 = fast_tanh(acc0[2] + b20.z), h03 = fast_tanh(acc0[3] + b20.w);
            float h10 = fast_tanh(acc1[0] + b21.x), h11 = fast_tanh(acc1[1] + b21.y);
            float h12 = fast_tanh(acc1[2] + b21.z), h13 = fast_tanh(acc1[3] + b21.w);
            u32 gp00 = pkbf((1.f-h00*h00)*w30.x, (1.f-h01*h01)*w30.y);
            u32 gp01 = pkbf((1.f-h02*h02)*w30.z, (1.f-h03*h03)*w30.w);
            u32 gp10 = pkbf((1.f-h10*h10)*w31.x, (1.f-h11*h11)*w31.y);
            u32 gp11 = pkbf((1.f-h12*h12)*w31.z, (1.f-h13*h13)*w31.w);
            gf[T] = t1frag(gp00, gp01, gp10, gp11, thi, a1, a2);
        }

        // ---- GEMM3t + G1, tile-paired (dp recomputed from hp) ----
        bf16x8 g1f[4];
        #pragma unroll
        for (int T = 0; T < 4; ++T) {
            floatx4 sa0 = {0.f,0.f,0.f,0.f}, sa1 = {0.f,0.f,0.f,0.f};
            #pragma unroll
            for (int jt2 = 0; jt2 < 4; ++jt2) {
                sa0 = __builtin_amdgcn_mfma_f32_16x16x32_bf16(
                    ldfrag(sW2R, (2*T)*4 + jt2,     lane), gf[jt2], sa0, 0, 0, 0);
                sa1 = __builtin_amdgcn_mfma_f32_16x16x32_bf16(
                    ldfrag(sW2R, (2*T + 1)*4 + jt2, lane), gf[jt2], sa1, 0, 0, 0);
            }
            float h00 = unplo(hp[2*T][0]),   h01 = unphi(hp[2*T][0]);
            float h02 = unplo(hp[2*T][1]),   h03 = unphi(hp[2*T][1]);
            float h10 = unplo(hp[2*T+1][0]), h11 = unphi(hp[2*T+1][0]);
            float h12 = unplo(hp[2*T+1][1]), h13 = unphi(hp[2*T+1][1]);
            u32 g00 = pkbf((1.f-h00*h00)*sa0[0], (1.f-h01*h01)*sa0[1]);
            u32 g01 = pkbf((1.f-h02*h02)*sa0[2], (1.f-h03*h03)*sa0[3]);
            u32 g10 = pkbf((1.f-h10*h10)*sa1[0], (1.f-h11*h11)*sa1[1]);
            u32 g11 = pkbf((1.f-h12*h12)*sa1[2], (1.f-h13*h13)*sa1[3]);
            g1f[T] = t1frag(g00, g01, g10, g11, thi, a1, a2);
        }

        // ---- GEMM4t: dV^T = W1 @ G1^T ----
        floatx4 dv = floatx4{0.f,0.f,0.f,0.f};
        #pragma unroll
        for (int it3 = 0; it3 < 4; ++it3)
            dv = __builtin_amdgcn_mfma_f32_16x16x32_bf16(
                ldfrag(sW1f, it3, lane), g1f[it3], dv, 0, 0, 0);

        // ---- epilogue: analytic dynamics + 2x2 solve (quad-0 lanes) ----
        if (q == 0 && g < B) {
            float w1 = x.z, w2 = x.w;
            float cosD = c1v * c2v + s1v * s2v;
            float sinD = s1v * c2v - c1v * s2v;
            float dVt1 = dv[0] * c1v - dv[1] * s1v;  // dV/dt1
            float dVt2 = dv[2] * c2v - dv[3] * s2v;  // dV/dt2
            float sT = w1 * w2 * sinD;               // dT/dt1=-sT, dT/dt2=+sT
            float cw = sinD * (w2 - w1);
            float rhs1 = (-sT - dVt1) - w2 * cw;
            float rhs2 = ( sT - dVt2) - w1 * cw;
            float det = 2.0f - cosD * cosD;          // det(M) in [1,2]
            float inv = 1.0f / det;
            float qdd1 = (rhs1 - cosD * rhs2) * inv;
            float qdd2 = (2.0f * rhs2 - cosD * rhs1) * inv;
            *reinterpret_cast<float4*>(&out[4 * g]) = make_float4(w1, w2, qdd1, qdd2);
        }
    }
}

extern "C" void kernel_launch(void* const* d_in, const int* in_sizes, int n_in,
                              void* d_out, int out_size, void* d_ws, size_t ws_size,
                              hipStream_t stream) {
    const float* X  = (const float*)d_in[0];
    const float* W1 = (const float*)d_in[1];
    const float* b1 = (const float*)d_in[2];
    const float* W2 = (const float*)d_in[3];
    const float* b2 = (const float*)d_in[4];
    const float* W3 = (const float*)d_in[5];
    // d_in[6] = b3: constant offset on V, vanishes in all gradients
    float* out = (float*)d_out;
    int B = in_sizes[0] / 4;
    int spg = GRIDB * (TPB / 4); // samples per grid-chunk
    int nchunk = (B + spg - 1) / spg;
    lnn_kernel<<<GRIDB, TPB, 0, stream>>>(X, W1, b1, b2, W3, W2, out, B, nchunk);
}

// Round 12
// 167.252 us; speedup vs baseline: 1.7617x; 1.6434x over previous
//
#include <hip/hip_runtime.h>
#include <math.h>

#define HID 128
#define TPB 256    // 4 waves/block; launch_bounds(256,2) -> 256 VGPRs/wave, no spill
#define GRIDB 1024 // persistent; 64 samples per block-chunk; nchunk = 2

typedef __bf16 bf16;
typedef bf16 bf16x8 __attribute__((ext_vector_type(8)));
typedef bf16 bf16x2 __attribute__((ext_vector_type(2)));
typedef float floatx4 __attribute__((ext_vector_type(4)));
typedef unsigned int u32;

__device__ __forceinline__ float fast_tanh(float x) {
    float e = __builtin_amdgcn_exp2f(x * 2.885390081777927f); // exp(2x)
    return 1.0f - 2.0f / (e + 1.0f);
}
__device__ __forceinline__ u32 pkbf(float lo, float hi) {
    bf16x2 t = {(bf16)lo, (bf16)hi};
    return __builtin_bit_cast(u32, t);
}
__device__ __forceinline__ float unplo(u32 p) {
    return __builtin_bit_cast(float, p << 16);
}
__device__ __forceinline__ float unphi(u32 p) {
    return __builtin_bit_cast(float, p & 0xffff0000u);
}
union FragU { bf16x8 v; u32 u[4]; };

// T1: C/D-layout -> B-frag layout, fully intra-wave (verified R10/R11).
//   D tile t: lane(q,c) reg r holds M[row=16t+4q+r][col=c]
//   frag tile T: lane(q,c) idx holds M[k=32T+8q+idx][n=c]
//   src tile 2T+(q>>1), src lane (2(q&1)+(idx>>2))*16+c, reg idx&3.
//   Dest-side tile select AFTER the shuffle (cndmask on dest q>>1).
__device__ __forceinline__ bf16x8 t1frag(u32 pA0, u32 pA1, u32 pB0, u32 pB1,
                                         bool hi, int a1, int a2) {
    u32 A0a = (u32)__shfl((int)pA0, a1);
    u32 A1a = (u32)__shfl((int)pA1, a1);
    u32 B0a = (u32)__shfl((int)pB0, a1);
    u32 B1a = (u32)__shfl((int)pB1, a1);
    u32 A0b = (u32)__shfl((int)pA0, a2);
    u32 A1b = (u32)__shfl((int)pA1, a2);
    u32 B0b = (u32)__shfl((int)pB0, a2);
    u32 B1b = (u32)__shfl((int)pB1, a2);
    FragU f;
    f.u[0] = hi ? B0a : A0a;
    f.u[1] = hi ? B1a : A1a;
    f.u[2] = hi ? B0b : A0b;
    f.u[3] = hi ? B1b : A1b;
    return f.v;
}
__device__ __forceinline__ bf16x8 ldfrag(const bf16* base, int tile, int lane) {
    return *reinterpret_cast<const bf16x8*>(&base[(tile * 64 + lane) * 8]);
}

// Wave owns a 16-sample stripe end-to-end; zero barriers in the main loop.
// R12: same math as R11; the fix is the register BUDGET (launch_bounds(256,2)
// -> 256 unified VGPRs/wave) so the ~160-200-reg demand stops spilling.

__global__ __launch_bounds__(TPB, 2)
void lnn_kernel(const float* __restrict__ X,
                const float* __restrict__ W1,
                const float* __restrict__ b1,
                const float* __restrict__ b2,
                const float* __restrict__ W3,
                const float* __restrict__ W2,
                float* __restrict__ out,
                int B, int nchunk)
{
    __shared__ __align__(16) bf16 sW2A[2048 * 8]; // 32KB W2^T A-frags [(jt*4+kt)]
    __shared__ __align__(16) bf16 sW2R[2048 * 8]; // 32KB W2 row A-frags [(it*4+jt2)]
    __shared__ __align__(16) bf16 sW1e[512 * 8];  // 8KB  W1ext^T A-frags [jt]
    __shared__ __align__(16) bf16 sW1f[256 * 8];  // 4KB  W1 A-frags [it3]
    __shared__ __align__(16) float sB2[HID];
    __shared__ __align__(16) float sW3[HID];

    const int tid = threadIdx.x;
    const int w   = tid >> 6;   // 0..3
    const int lane = tid & 63;
    const int c   = lane & 15;
    const int q   = lane >> 4;
    const int a1  = 32 * (q & 1) + c;
    const int a2  = a1 + 16;
    const bool thi = (q >> 1) != 0;

    // ------ one-time staging, 256-thread partition (re-derived for TPB=256) ------
    #pragma unroll
    for (int tt = 0; tt < 8; ++tt) {
        int e = tid + tt * TPB;           // 0..2047 frag lines
        int t = e >> 6, l = e & 63;
        int lr = l & 15, qq = l >> 4;
        {   // sW2A tile (jt,kt): A[m=16jt+lr][k=32kt+8qq+idx] = W2[k][m]
            int jt = t >> 2, kt = t & 3;
            bf16x8 f;
            #pragma unroll
            for (int idx = 0; idx < 8; ++idx)
                f[idx] = (bf16)W2[(32 * kt + 8 * qq + idx) * HID + 16 * jt + lr];
            *reinterpret_cast<bf16x8*>(&sW2A[e * 8]) = f;
        }
        {   // sW2R tile (it,jt2): A[m=16it+lr][k=32jt2+8qq+idx] = W2[m][k]
            int it = t >> 2, jt2 = t & 3;
            const float4* rp = reinterpret_cast<const float4*>(
                &W2[(16 * it + lr) * HID + 32 * jt2 + 8 * qq]);
            float4 r0 = rp[0], r1 = rp[1];
            bf16x8 g;
            g[0]=(bf16)r0.x; g[1]=(bf16)r0.y; g[2]=(bf16)r0.z; g[3]=(bf16)r0.w;
            g[4]=(bf16)r1.x; g[5]=(bf16)r1.y; g[6]=(bf16)r1.z; g[7]=(bf16)r1.w;
            *reinterpret_cast<bf16x8*>(&sW2R[e * 8]) = g;
        }
    }
    #pragma unroll
    for (int tt = 0; tt < 2; ++tt) { // sW1e (512 lines): A[m=16jt+lr][k=8qq+idx]
        int e = tid + tt * TPB;
        int t = e >> 6, l = e & 63;
        int lr = l & 15, qq = l >> 4;
        bf16x8 f = {};
        if (qq == 0) {
            #pragma unroll
            for (int idx = 0; idx < 4; ++idx)
                f[idx] = (bf16)W1[idx * HID + 16 * t + lr];
            f[4] = (bf16)b1[16 * t + lr];
        }
        *reinterpret_cast<bf16x8*>(&sW1e[e * 8]) = f;
    }
    {   // sW1f (256 lines, 1/thread): A[m=lr(<4)][k=32it3+8qq+idx] = W1[m][k]
        int t = tid >> 6, l = tid & 63;
        int lr = l & 15, qq = l >> 4;
        bf16x8 f = {};
        if (lr < 4) {
            const float4* wp = reinterpret_cast<const float4*>(
                &W1[lr * HID + 32 * t + 8 * qq]);
            float4 a = wp[0], b = wp[1];
            f[0]=(bf16)a.x; f[1]=(bf16)a.y; f[2]=(bf16)a.z; f[3]=(bf16)a.w;
            f[4]=(bf16)b.x; f[5]=(bf16)b.y; f[6]=(bf16)b.z; f[7]=(bf16)b.w;
        }
        *reinterpret_cast<bf16x8*>(&sW1f[tid * 8]) = f;
    }
    if (tid < 128)      sB2[tid] = b2[tid];
    else                sW3[tid - 128] = W3[tid - 128];
    __syncthreads(); // the ONLY barrier

    #pragma unroll 1
    for (int ch = 0; ch < nchunk; ++ch) {
        const int s0 = (ch * GRIDB + (int)blockIdx.x) * (TPB / 4); // 64/blk
        const int g  = s0 + 16 * w + c;
        const int gc = g < B ? g : (B - 1);

        float4 x = reinterpret_cast<const float4*>(X)[gc];
        float s1v, c1v, s2v, c2v;
        __sincosf(x.x, &s1v, &c1v);
        __sincosf(x.y, &s2v, &c2v);

        // feat^T B-frag (k<5 live, quad 0 only)
        FragU fb; fb.u[0] = fb.u[1] = fb.u[2] = fb.u[3] = 0;
        if (q == 0) {
            fb.u[0] = pkbf(s1v, c1v);
            fb.u[1] = pkbf(s2v, c2v);
            fb.u[2] = pkbf(1.0f, 0.0f);
        }

        // ---- Layer 1, tile-paired: z pair -> tanh -> hp pair -> hf[T] ----
        u32 hp[8][2];     // bf16-packed h1 in D-layout (kept for deriv recompute)
        bf16x8 hf[4];
        #pragma unroll
        for (int T = 0; T < 4; ++T) {
            floatx4 z0 = __builtin_amdgcn_mfma_f32_16x16x32_bf16(
                ldfrag(sW1e, 2*T,     lane), fb.v, floatx4{0.f,0.f,0.f,0.f}, 0, 0, 0);
            floatx4 z1 = __builtin_amdgcn_mfma_f32_16x16x32_bf16(
                ldfrag(sW1e, 2*T + 1, lane), fb.v, floatx4{0.f,0.f,0.f,0.f}, 0, 0, 0);
            float h00 = fast_tanh(z0[0]), h01 = fast_tanh(z0[1]);
            float h02 = fast_tanh(z0[2]), h03 = fast_tanh(z0[3]);
            float h10 = fast_tanh(z1[0]), h11 = fast_tanh(z1[1]);
            float h12 = fast_tanh(z1[2]), h13 = fast_tanh(z1[3]);
            hp[2*T][0]   = pkbf(h00, h01); hp[2*T][1]   = pkbf(h02, h03);
            hp[2*T+1][0] = pkbf(h10, h11); hp[2*T+1][1] = pkbf(h12, h13);
            hf[T] = t1frag(hp[2*T][0], hp[2*T][1], hp[2*T+1][0], hp[2*T+1][1],
                           thi, a1, a2);
        }

        // ---- GEMM2t + activation, tile-paired ----
        bf16x8 gf[4];
        #pragma unroll
        for (int T = 0; T < 4; ++T) {
            floatx4 acc0 = {0.f,0.f,0.f,0.f}, acc1 = {0.f,0.f,0.f,0.f};
            #pragma unroll
            for (int kt = 0; kt < 4; ++kt) {
                acc0 = __builtin_amdgcn_mfma_f32_16x16x32_bf16(
                    ldfrag(sW2A, (2*T)*4 + kt,     lane), hf[kt], acc0, 0, 0, 0);
                acc1 = __builtin_amdgcn_mfma_f32_16x16x32_bf16(
                    ldfrag(sW2A, (2*T + 1)*4 + kt, lane), hf[kt], acc1, 0, 0, 0);
            }
            float4 b20 = *reinterpret_cast<const float4*>(&sB2[16*(2*T)   + 4*q]);
            float4 w30 = *reinterpret_cast<const float4*>(&sW3[16*(2*T)   + 4*q]);
            float4 b21 = *reinterpret_cast<const float4*>(&sB2[16*(2*T+1) + 4*q]);
            float4 w31 = *reinterpret_cast<const float4*>(&sW3[16*(2*T+1) + 4*q]);
            float h00 = fast_tanh(acc0[0] + b20.x), h01 = fast_tanh(acc0[1] + b20.y);
            float h02 = fast_tanh(acc0[2] + b20.z), h03 = fast_tanh(acc0[3] + b20.w);
            float h10 = fast_tanh(acc1[0] + b21.x), h11 = fast_tanh(acc1[1] + b21.y);
            float h12 = fast_tanh(acc1[2] + b21.z), h13 = fast_tanh(acc1[3] + b21.w);
            u32 gp00 = pkbf((1.f-h00*h00)*w30.x, (1.f-h01*h01)*w30.y);
            u32 gp01 = pkbf((1.f-h02*h02)*w30.z, (1.f-h03*h03)*w30.w);
            u32 gp10 = pkbf((1.f-h10*h10)*w31.x, (1.f-h11*h11)*w31.y);
            u32 gp11 = pkbf((1.f-h12*h12)*w31.z, (1.f-h13*h13)*w31.w);
            gf[T] = t1frag(gp00, gp01, gp10, gp11, thi, a1, a2);
        }

        // ---- GEMM3t + G1, tile-paired (deriv recomputed from hp) ----
        bf16x8 g1f[4];
        #pragma unroll
        for (int T = 0; T < 4; ++T) {
            floatx4 sa0 = {0.f,0.f,0.f,0.f}, sa1 = {0.f,0.f,0.f,0.f};
            #pragma unroll
            for (int jt2 = 0; jt2 < 4; ++jt2) {
                sa0 = __builtin_amdgcn_mfma_f32_16x16x32_bf16(
                    ldfrag(sW2R, (2*T)*4 + jt2,     lane), gf[jt2], sa0, 0, 0, 0);
                sa1 = __builtin_amdgcn_mfma_f32_16x16x32_bf16(
                    ldfrag(sW2R, (2*T + 1)*4 + jt2, lane), gf[jt2], sa1, 0, 0, 0);
            }
            float h00 = unplo(hp[2*T][0]),   h01 = unphi(hp[2*T][0]);
            float h02 = unplo(hp[2*T][1]),   h03 = unphi(hp[2*T][1]);
            float h10 = unplo(hp[2*T+1][0]), h11 = unphi(hp[2*T+1][0]);
            float h12 = unplo(hp[2*T+1][1]), h13 = unphi(hp[2*T+1][1]);
            u32 g00 = pkbf((1.f-h00*h00)*sa0[0], (1.f-h01*h01)*sa0[1]);
            u32 g01 = pkbf((1.f-h02*h02)*sa0[2], (1.f-h03*h03)*sa0[3]);
            u32 g10 = pkbf((1.f-h10*h10)*sa1[0], (1.f-h11*h11)*sa1[1]);
            u32 g11 = pkbf((1.f-h12*h12)*sa1[2], (1.f-h13*h13)*sa1[3]);
            g1f[T] = t1frag(g00, g01, g10, g11, thi, a1, a2);
        }

        // ---- GEMM4t: dV^T = W1 @ G1^T ----
        floatx4 dv = floatx4{0.f,0.f,0.f,0.f};
        #pragma unroll
        for (int it3 = 0; it3 < 4; ++it3)
            dv = __builtin_amdgcn_mfma_f32_16x16x32_bf16(
                ldfrag(sW1f, it3, lane), g1f[it3], dv, 0, 0, 0);

        // ---- epilogue: analytic dynamics + 2x2 solve (quad-0 lanes) ----
        if (q == 0 && g < B) {
            float w1 = x.z, w2 = x.w;
            float cosD = c1v * c2v + s1v * s2v;
            float sinD = s1v * c2v - c1v * s2v;
            float dVt1 = dv[0] * c1v - dv[1] * s1v;  // dV/dt1
            float dVt2 = dv[2] * c2v - dv[3] * s2v;  // dV/dt2
            float sT = w1 * w2 * sinD;               // dT/dt1=-sT, dT/dt2=+sT
            float cw = sinD * (w2 - w1);
            float rhs1 = (-sT - dVt1) - w2 * cw;
            float rhs2 = ( sT - dVt2) - w1 * cw;
            float det = 2.0f - cosD * cosD;          // det(M) in [1,2]
            float inv = 1.0f / det;
            float qdd1 = (rhs1 - cosD * rhs2) * inv;
            float qdd2 = (2.0f * rhs2 - cosD * rhs1) * inv;
            *reinterpret_cast<float4*>(&out[4 * g]) = make_float4(w1, w2, qdd1, qdd2);
        }
    }
}

extern "C" void kernel_launch(void* const* d_in, const int* in_sizes, int n_in,
                              void* d_out, int out_size, void* d_ws, size_t ws_size,
                              hipStream_t stream) {
    const float* X  = (const float*)d_in[0];
    const float* W1 = (const float*)d_in[1];
    const float* b1 = (const float*)d_in[2];
    const float* W2 = (const float*)d_in[3];
    const float* b2 = (const float*)d_in[4];
    const float* W3 = (const float*)d_in[5];
    // d_in[6] = b3: constant offset on V, vanishes in all gradients
    float* out = (float*)d_out;
    int B = in_sizes[0] / 4;
    int spg = GRIDB * (TPB / 4); // samples per grid-chunk
    int nchunk = (B + spg - 1) / spg;
    lnn_kernel<<<GRIDB, TPB, 0, stream>>>(X, W1, b1, b2, W3, W2, out, B, nchunk);
}